// Round 2
// baseline (784.746 us; speedup 1.0000x reference)
//
#include <hip/hip_runtime.h>
#include <cstdint>

// ---------------------------------------------------------------------------
// DDPM + VAE query encoder, MI355X round 14.
// r13 post-mortem: rotate/hoist micro-fixes neutral -> instruction stream was
// already clean. Counter re-derivation: MfmaUtil 6.8% == 4 x static 1.9%
// per-SIMD -> derived counters are per-CU any-of-4-SIMD rates. Real per-SIMD
// VALU issue ~36% -> k_ddpm is LATENCY/BARRIER-bound at 4 waves/SIMD (grid
// 512 blocks = 2/CU), not issue-bound.
// Fix: wave specialization. 1024-thread blocks (16 waves): even waves =
// compute (r13 structure verbatim), odd waves = PRNG producers running one
// step ahead into a double-buffered LDS nbuf[2][1024]. 512 blocks x 16 waves
// = 8192 waves = 8 waves/SIMD (full occupancy). Noise floats bit-identical
// (same threefry path, staged via LDS) -> absmax unchanged.
// ---------------------------------------------------------------------------

#define DEVI __device__ __forceinline__

typedef __attribute__((ext_vector_type(8))) short short8;
typedef __attribute__((ext_vector_type(4))) float f32x4;

DEVI void threefry2x32(uint32_t k0, uint32_t k1, uint32_t x0, uint32_t x1,
                       uint32_t &o0, uint32_t &o1)
{
  const uint32_t ks2 = k0 ^ k1 ^ 0x1BD11BDAu;
  x0 += k0; x1 += k1;
#define TFR(r) { x0 += x1; x1 = __builtin_rotateleft32(x1, r); x1 ^= x0; }
  TFR(13u) TFR(15u) TFR(26u) TFR(6u)   x0 += k1;  x1 += ks2 + 1u;
  TFR(17u) TFR(29u) TFR(16u) TFR(24u)  x0 += ks2; x1 += k0 + 2u;
  TFR(13u) TFR(15u) TFR(26u) TFR(6u)   x0 += k0;  x1 += k1 + 3u;
  TFR(17u) TFR(29u) TFR(16u) TFR(24u)  x0 += k1;  x1 += ks2 + 4u;
  TFR(13u) TFR(15u) TFR(26u) TFR(6u)   x0 += ks2; x1 += k0 + 5u;
#undef TFR
  o0 = x0; o1 = x1;
}

DEVI uint32_t jax_random_bits32(uint32_t k0, uint32_t k1, uint32_t j)
{
  uint32_t a, b;
  threefry2x32(k0, k1, 0u, j, a, b);
  return a ^ b;
}

DEVI float jax_bits_to_normal(uint32_t bits)
{
  const float LO = -0.99999994f;
  float f = __uint_as_float((bits >> 9) | 0x3f800000u) - 1.0f;
  float u = fmaxf(LO, f * 2.0f + LO);
  float w = -__logf((1.0f - u) * (1.0f + u));
  float p;
  if (w < 5.0f) {
    w = w - 2.5f;
    p =              2.81022636e-08f;
    p = fmaf(p, w,   3.43273939e-07f);
    p = fmaf(p, w,  -3.5233877e-06f);
    p = fmaf(p, w,  -4.39150654e-06f);
    p = fmaf(p, w,   0.00021858087f);
    p = fmaf(p, w,  -0.00125372503f);
    p = fmaf(p, w,  -0.00417768164f);
    p = fmaf(p, w,   0.246640727f);
    p = fmaf(p, w,   1.50140941f);
  } else {
    w = sqrtf(w) - 3.0f;
    p =             -0.000200214257f;
    p = fmaf(p, w,   0.000100950558f);
    p = fmaf(p, w,   0.00134934322f);
    p = fmaf(p, w,  -0.00367342844f);
    p = fmaf(p, w,   0.00573950773f);
    p = fmaf(p, w,  -0.0076224613f);
    p = fmaf(p, w,   0.00943887047f);
    p = fmaf(p, w,   1.00167406f);
    p = fmaf(p, w,   2.83297682f);
  }
  return 1.41421356237f * (p * u);
}

DEVI short bf16_hi_trunc(float x) { return (short)(__float_as_uint(x) >> 16); }
DEVI float bf16_to_f32(short h)
{
  return __uint_as_float(((uint32_t)(unsigned short)h) << 16);
}
DEVI void split_bf16(float x, short &h, short &l)
{
  h = bf16_hi_trunc(x);
  float r = x - bf16_to_f32(h);
  l = bf16_hi_trunc(r);
}

// 8-short fragment from 8B-aligned LDS (stride-68 rows): two b64 reads.
DEVI short8 ld_frag(const short* p)
{
  union { int4 v; short8 s; } u;
  const int2* q = (const int2*)p;
  int2 a = q[0], b = q[1];
  u.v = make_int4(a.x, a.y, b.x, b.y);
  return u.s;
}

// ---------------------------------------------------------------------------
__global__ __launch_bounds__(256)
void k_pool(const int* __restrict__ seq, const float* __restrict__ emb,
            float* __restrict__ pooled)
{
  const int lane = threadIdx.x & 63;
  const int r    = blockIdx.x * 4 + (threadIdx.x >> 6);
  const int* row = seq + r * 100;
  float s = 0.f;
  int cnt = 0;
  for (int l = 0; l < 100; ++l) {
    int id = row[l];
    cnt += (id != 0);
    s += emb[id * 64 + lane];
  }
  pooled[r * 64 + lane] = s / sqrtf((float)cnt);
}

// ---------------------------------------------------------------------------
__global__ __launch_bounds__(256)
void k_enc(const float* __restrict__ pooled,
           const float* __restrict__ W1, const float* __restrict__ b1,
           const float* __restrict__ W2, const float* __restrict__ b2,
           const float* __restrict__ Wc, const float* __restrict__ bc,
           float* __restrict__ cproj)
{
  __shared__ float p_s[8][64];
  __shared__ float h_s[8][256];
  __shared__ float mu_s[8][64];
  const int tid = threadIdx.x;
  const int r0  = blockIdx.x * 8;

  for (int i = tid; i < 8 * 64; i += 256)
    p_s[i >> 6][i & 63] = pooled[r0 * 64 + i];
  __syncthreads();

  float hacc[8];
#pragma unroll
  for (int r = 0; r < 8; ++r) hacc[r] = b1[tid];
  for (int k = 0; k < 64; ++k) {
    float w = W1[k * 256 + tid];
#pragma unroll
    for (int r = 0; r < 8; ++r) hacc[r] = fmaf(p_s[r][k], w, hacc[r]);
  }
#pragma unroll
  for (int r = 0; r < 8; ++r) h_s[r][tid] = fmaxf(hacc[r], 0.f);
  __syncthreads();

#pragma unroll
  for (int pass = 0; pass < 2; ++pass) {
    int r = pass * 4 + (tid >> 6);
    int j = tid & 63;
    float acc = b2[j];
    for (int k = 0; k < 256; ++k)
      acc = fmaf(h_s[r][k], W2[k * 128 + j], acc);
    mu_s[r][j] = acc;
  }
  __syncthreads();

#pragma unroll
  for (int pass = 0; pass < 2; ++pass) {
    int r = pass * 4 + (tid >> 6);
    int j = tid & 63;
    float acc = bc[j];
    for (int k = 0; k < 64; ++k)
      acc = fmaf(mu_s[r][k], Wc[k * 64 + j], acc);
    cproj[(r0 + r) * 64 + j] = acc;
  }
}

// ---------------------------------------------------------------------------
// k_prep: 200 blocks x 64 threads. Block t computes sched[t*8+..] AND
// tpb[t][d] = temb(t)@W_t + b_t + b_in.
__global__ __launch_bounds__(64)
void k_prep(const float* __restrict__ Wt, const float* __restrict__ bt,
            const float* __restrict__ bin, float* __restrict__ tpb,
            float* __restrict__ sched)
{
  __shared__ float temb[64];
  const int t = blockIdx.x;
  const int d = threadIdx.x;
  const float lg = logf(10000.0f);
  {
    int i = d & 31;
    float fr  = expf((-lg * (float)i) / 32.0f);
    float ang = (float)t * fr;
    temb[d] = (d < 32) ? cosf(ang) : sinf(ang);
  }
  if (d == 0) {
    const float start = (float)(5.0 * 1e-4);
    const float stop  = (float)(5.0 * 0.02);
    const float delta = stop - start;
    float prod = 1.f, acp_prev = 1.f, beta = 0.f, alpha = 1.f;
    for (int i = 0; i <= t; ++i) {
      beta  = start + ((float)i * delta) / 199.0f;
      alpha = 1.0f - beta;
      acp_prev = prod;
      prod = prod * alpha;
    }
    float acp = prod;
    float om  = 1.0f - acp;
    sched[t * 8 + 0] = sqrtf(1.0f / acp);
    sched[t * 8 + 1] = sqrtf(1.0f / acp - 1.0f);
    sched[t * 8 + 2] = beta * sqrtf(acp_prev) / om;
    sched[t * 8 + 3] = (1.0f - acp_prev) * sqrtf(alpha) / om;
    float pv = beta * (1.0f - acp_prev) / om;
    sched[t * 8 + 4] = (t > 0) ? sqrtf(pv) : 0.0f;
    uint32_t fk0, fk1;
    threefry2x32(0u, 2u, 0u, (uint32_t)t, fk0, fk1);
    ((uint32_t*)sched)[t * 8 + 5] = fk0;
    ((uint32_t*)sched)[t * 8 + 6] = fk1;
  }
  __syncthreads();
  float acc = bt[d] + bin[d];
  for (int k = 0; k < 64; ++k)
    acc = fmaf(temb[k], Wt[k * 64 + d], acc);
  tpb[t * 64 + d] = acc;
}

// ---------------------------------------------------------------------------
// K_ddpm: 512 blocks x 1024 threads (16 waves). Block owns 16 rows.
// Even waves (cw = w>>1, 8 of them): compute, r13 structure:
//   nt=cw&3 (cols 16nt..16nt+15), kc=cw>>2 (K-chunk [32kc,32kc+32)).
//   Wave kc owns C-rows {quad*4+2kc, quad*4+2kc+1} end-to-end.
// Odd waves (nw = w>>1): PRNG producers; wave nw draws noise for block-local
//   rows {2nw, 2nw+1} of step t-1 into nbuf[(t-1)&1] while compute chews t.
// Roles by wave PARITY so either wave->SIMD mapping (w&3 or w>>2) balances.
#define WLDW  68   // weight row stride (shorts)
#define XLDW  68   // X/H row stride (shorts)
#define PACCW 10   // pacc row stride (floats): float2 per quad

__global__
__attribute__((amdgpu_flat_work_group_size(1024, 1024), amdgpu_waves_per_eu(8)))
void k_ddpm(const float* __restrict__ Win, const float* __restrict__ Wout,
            const float* __restrict__ bout,
            const float* __restrict__ cproj, const float* __restrict__ tpb,
            const float* __restrict__ sched, float* __restrict__ out)
{
  __shared__ short WiHs[64 * WLDW], WiLs[64 * WLDW];
  __shared__ short WoHs[64 * WLDW], WoLs[64 * WLDW];
  __shared__ short Xh[16 * XLDW], Xl[16 * XLDW], Hh[16 * XLDW], Hl[16 * XLDW];
  __shared__ float pacc[2 * 64 * PACCW];
  __shared__ float nbuf[2 * 1024];          // double-buffered noise, fp32
  // total: 34816 + 8704 + 5120 + 8192 = 56832 B -> 2 blocks/CU (thread-cap too)

  const int tid  = threadIdx.x;
  const int lane = tid & 63;
  const int w    = tid >> 6;
  const bool isCompute = (w & 1) == 0;
  const int r0g  = blockIdx.x * 16;
  const uint32_t* su = (const uint32_t*)sched;

  // ---- stage split weights, transposed [n][k] (all 16 waves)
  for (int idx = tid; idx < 4096; idx += 1024) {
    int k = idx >> 6, n = idx & 63;
    short h, l;
    split_bf16(Win[idx], h, l);
    WiHs[n * WLDW + k] = h; WiLs[n * WLDW + k] = l;
    split_bf16(Wout[idx], h, l);
    WoHs[n * WLDW + k] = h; WoLs[n * WLDW + k] = l;
  }

  // ---- role-specific setup --------------------------------------------------
  // compute-wave ids
  const int cw   = w >> 1;
  const int nt   = cw & 3;
  const int kc   = cw >> 2;
  const int nn   = lane & 15;
  const int quad = lane >> 4;
  const int dim  = nt * 16 + nn;
  const int arow = nn;
  const int kofs = kc * 32 + quad * 8;
  const int rA   = quad * 4 + 2 * kc;       // owned C-rows rA, rA+1

  // noise-wave ids: rows {2nw, 2nw+1}, dim = lane
  const int nw = w >> 1;
  const uint32_t jn0 = (uint32_t)((r0g + 2 * nw) * 64 + lane);
  const uint32_t jn1 = jn0 + 64u;
  const int wi0 = 2 * nw * 64 + lane;
  const int wi1 = wi0 + 64;

  float xoA = 0.f, xoB = 0.f, cpA = 0.f, cpB = 0.f, bo = 0.f, tp = 0.f;
  uint32_t jA = 0, jB = 0;
  float* pacc_w = nullptr;
  const float* pacc_r = nullptr;

  if (isCompute) {
    bo  = bout[dim];
    jA  = (uint32_t)((r0g + rA) * 64 + dim);
    jB  = jA + 64u;
    cpA = cproj[jA];
    cpB = cproj[jB];
    // x_init at owned positions
    xoA = jax_bits_to_normal(jax_random_bits32(0u, 1u, jA));
    xoB = jax_bits_to_normal(jax_random_bits32(0u, 1u, jB));
    short h, l;
    split_bf16(xoA, h, l); Xh[rA * XLDW + dim] = h; Xl[rA * XLDW + dim] = l;
    split_bf16(xoB, h, l); Xh[(rA+1) * XLDW + dim] = h; Xl[(rA+1) * XLDW + dim] = l;
    tp = tpb[199 * 64 + dim];
    pacc_w = &pacc[(kc * 64 + dim) * PACCW + quad * 2];
    pacc_r = &pacc[((1 - kc) * 64 + dim) * PACCW + quad * 2];
  } else {
    // pre-draw noise for t=199 into nbuf[199&1 == 1]
    uint32_t gk0 = su[199 * 8 + 5];
    uint32_t gk1 = su[199 * 8 + 6];
    nbuf[1024 + wi0] = jax_bits_to_normal(jax_random_bits32(gk0, gk1, jn0));
    nbuf[1024 + wi1] = jax_bits_to_normal(jax_random_bits32(gk0, gk1, jn1));
  }
  __syncthreads();

#pragma unroll 1
  for (int t = 199; t >= 0; --t) {
    // -------- segment A (before B1) --------
    float nA = 0.f, nB = 0.f;
    float sr = 0.f, srm1 = 0.f, c1 = 0.f, c2 = 0.f, sg = 0.f;
    f32x4 acc;
    uint32_t gk0 = 0, gk1 = 0;
    float* ndst = nullptr;

    if (isCompute) {
      sr   = sched[t * 8 + 0];
      srm1 = sched[t * 8 + 1];
      c1   = sched[t * 8 + 2];
      c2   = sched[t * 8 + 3];
      sg   = sched[t * 8 + 4];
      // noise for this step: produced >=1 iteration ago, buffer t&1
      const float* nb = nbuf + (t & 1) * 1024;
      nA = nb[rA * 64 + dim];
      nB = nb[rA * 64 + 64 + dim];

      // ---- phase 1: in-GEMV partial over own K-chunk (bias on owned rows)
      if (kc == 0) { acc[0] = tp + cpA; acc[1] = tp + cpB; acc[2] = 0.f; acc[3] = 0.f; }
      else         { acc[0] = 0.f; acc[1] = 0.f; acc[2] = tp + cpA; acc[3] = tp + cpB; }
      {
        short8 ah = ld_frag(&Xh[arow * XLDW + kofs]);
        short8 al = ld_frag(&Xl[arow * XLDW + kofs]);
        short8 bh = ld_frag(&WiHs[dim * WLDW + kofs]);
        short8 bl = ld_frag(&WiLs[dim * WLDW + kofs]);
        acc = __builtin_amdgcn_mfma_f32_16x16x32_bf16(al, bh, acc, 0, 0, 0);
        acc = __builtin_amdgcn_mfma_f32_16x16x32_bf16(ah, bl, acc, 0, 0, 0);
        acc = __builtin_amdgcn_mfma_f32_16x16x32_bf16(ah, bh, acc, 0, 0, 0);
      }
      if (kc == 0) *(float2*)pacc_w = make_float2(acc[2], acc[3]);
      else         *(float2*)pacc_w = make_float2(acc[0], acc[1]);
    } else if (t > 0) {
      // produce noise for step t-1 (first half)
      gk0 = su[(t - 1) * 8 + 5];
      gk1 = su[(t - 1) * 8 + 6];
      ndst = nbuf + ((t - 1) & 1) * 1024;
      ndst[wi0] = jax_bits_to_normal(jax_random_bits32(gk0, gk1, jn0));
    }
    __syncthreads();                                    // B1

    // -------- segment B --------
    if (isCompute) {
      // ---- phase 2: finalize h for owned rows, silu, stage H
      float2 o = *(const float2*)pacc_r;
      float vA, vB;
      if (kc == 0) { vA = acc[0] + o.x; vB = acc[1] + o.y; }
      else         { vA = acc[2] + o.x; vB = acc[3] + o.y; }
      vA = vA * __builtin_amdgcn_rcpf(1.0f + __expf(-vA));
      vB = vB * __builtin_amdgcn_rcpf(1.0f + __expf(-vB));
      short h, l;
      split_bf16(vA, h, l); Hh[rA * XLDW + dim] = h; Hl[rA * XLDW + dim] = l;
      split_bf16(vB, h, l); Hh[(rA+1) * XLDW + dim] = h; Hl[(rA+1) * XLDW + dim] = l;
    } else if (t > 0) {
      // produce noise for step t-1 (second half)
      ndst[wi1] = jax_bits_to_normal(jax_random_bits32(gk0, gk1, jn1));
    }
    int tn = (t > 0) ? (t - 1) : 0;
    float tpn = isCompute ? tpb[tn * 64 + dim] : 0.f;   // prefetch next tp
    __syncthreads();                                    // B2

    // -------- segment C --------
    f32x4 eac;
    if (isCompute) {
      // ---- phase 3: out-GEMV partial (bias on owned rows)
      if (kc == 0) { eac[0] = bo; eac[1] = bo; eac[2] = 0.f; eac[3] = 0.f; }
      else         { eac[0] = 0.f; eac[1] = 0.f; eac[2] = bo; eac[3] = bo; }
      {
        short8 ah = ld_frag(&Hh[arow * XLDW + kofs]);
        short8 al = ld_frag(&Hl[arow * XLDW + kofs]);
        short8 bh = ld_frag(&WoHs[dim * WLDW + kofs]);
        short8 bl = ld_frag(&WoLs[dim * WLDW + kofs]);
        eac = __builtin_amdgcn_mfma_f32_16x16x32_bf16(al, bh, eac, 0, 0, 0);
        eac = __builtin_amdgcn_mfma_f32_16x16x32_bf16(ah, bl, eac, 0, 0, 0);
        eac = __builtin_amdgcn_mfma_f32_16x16x32_bf16(ah, bh, eac, 0, 0, 0);
      }
      if (kc == 0) *(float2*)pacc_w = make_float2(eac[2], eac[3]);
      else         *(float2*)pacc_w = make_float2(eac[0], eac[1]);
    }
    __syncthreads();                                    // B3

    // -------- segment D --------
    if (isCompute) {
      // ---- phase 4: finalize eps for owned rows, update, restage X
      float2 o = *(const float2*)pacc_r;
      float eA, eB;
      if (kc == 0) { eA = eac[0] + o.x; eB = eac[1] + o.y; }
      else         { eA = eac[2] + o.x; eB = eac[3] + o.y; }
      float xcA = fminf(1.f, fmaxf(-1.f, sr * xoA - srm1 * eA));
      float xcB = fminf(1.f, fmaxf(-1.f, sr * xoB - srm1 * eB));
      xoA = c1 * xcA + c2 * xoA + sg * nA;
      xoB = c1 * xcB + c2 * xoB + sg * nB;
      short h, l;
      split_bf16(xoA, h, l); Xh[rA * XLDW + dim] = h; Xl[rA * XLDW + dim] = l;
      split_bf16(xoB, h, l); Xh[(rA+1) * XLDW + dim] = h; Xl[(rA+1) * XLDW + dim] = l;
      tp = tpn;
    }
    __syncthreads();                                    // B4
  }

  if (isCompute) {
    out[jA] = xoA;
    out[jB] = xoB;
  }
}

// ---------------------------------------------------------------------------
extern "C" void kernel_launch(void* const* d_in, const int* in_sizes, int n_in,
                              void* d_out, int out_size, void* d_ws, size_t ws_size,
                              hipStream_t stream)
{
  const int*   seq  = (const int*)  d_in[0];
  const float* emb  = (const float*)d_in[1];
  const float* W1   = (const float*)d_in[2];
  const float* b1   = (const float*)d_in[3];
  const float* W2   = (const float*)d_in[4];
  const float* b2   = (const float*)d_in[5];
  const float* Win  = (const float*)d_in[6];
  const float* bin  = (const float*)d_in[7];
  const float* Wt   = (const float*)d_in[8];
  const float* bt   = (const float*)d_in[9];
  const float* Wc   = (const float*)d_in[10];
  const float* bc   = (const float*)d_in[11];
  const float* Wout = (const float*)d_in[12];
  const float* bout = (const float*)d_in[13];

  float* out   = (float*)d_out;
  float* ws    = (float*)d_ws;
  float* cproj = ws;                       // 524288 floats
  float* tpb   = ws + 524288;              // 12800 floats
  float* sched = ws + 524288 + 12800;      // 1600 floats (t*8 layout)
  float* pooled = out;                     // reuse d_out as scratch

  k_pool <<<2048, 256, 0, stream>>>(seq, emb, pooled);
  k_enc  <<<1024, 256, 0, stream>>>(pooled, W1, b1, W2, b2, Wc, bc, cproj);
  k_prep <<<200, 64, 0, stream>>>(Wt, bt, bin, tpb, sched);
  k_ddpm <<<512, 1024, 0, stream>>>(Win, Wout, bout, cproj, tpb, sched, out);
}

// Round 3
// 591.477 us; speedup vs baseline: 1.3268x; 1.3268x over previous
//
#include <hip/hip_runtime.h>
#include <cstdint>

// ---------------------------------------------------------------------------
// DDPM + VAE query encoder, MI355X round 15.
// r14 post-mortem: waves_per_eu(8) -> VGPR 32 -> scratch spills (WRITE_SIZE
// 2->10 MB) + 16-wave barriers; regression was a confound, not a falsification
// of the latency theory. r15 attacks the serial chain directly:
//  - Each wave now computes the FULL K=64 GEMV (6 MFMA, duplicated across the
//    old kc pair). MFMA util was 6.8% -> duplication is free. This removes the
//    pacc partial exchange entirely: 4 barriers/step -> 2, no pacc LDS traffic.
//  - LDS row stride 68 -> 72 shorts: every fragment 16B-aligned -> one
//    ds_read_b128 per fragment (bank math: 2-way max aliasing = free).
//  - Back to 512 blocks x 512 threads, waves_per_eu(4,4) (proven spill-free).
// Arithmetic: fp32 accumulation order within the dot changes (chunk1 now
// accumulates into the same MFMA acc instead of being summed as a partial);
// difference is ~1 ulp-level, far below the bf16-split tolerance (2^-8).
// ---------------------------------------------------------------------------

#define DEVI __device__ __forceinline__

typedef __attribute__((ext_vector_type(8))) short short8;
typedef __attribute__((ext_vector_type(4))) float f32x4;

DEVI void threefry2x32(uint32_t k0, uint32_t k1, uint32_t x0, uint32_t x1,
                       uint32_t &o0, uint32_t &o1)
{
  const uint32_t ks2 = k0 ^ k1 ^ 0x1BD11BDAu;
  x0 += k0; x1 += k1;
#define TFR(r) { x0 += x1; x1 = __builtin_rotateleft32(x1, r); x1 ^= x0; }
  TFR(13u) TFR(15u) TFR(26u) TFR(6u)   x0 += k1;  x1 += ks2 + 1u;
  TFR(17u) TFR(29u) TFR(16u) TFR(24u)  x0 += ks2; x1 += k0 + 2u;
  TFR(13u) TFR(15u) TFR(26u) TFR(6u)   x0 += k0;  x1 += k1 + 3u;
  TFR(17u) TFR(29u) TFR(16u) TFR(24u)  x0 += k1;  x1 += ks2 + 4u;
  TFR(13u) TFR(15u) TFR(26u) TFR(6u)   x0 += ks2; x1 += k0 + 5u;
#undef TFR
  o0 = x0; o1 = x1;
}

DEVI uint32_t jax_random_bits32(uint32_t k0, uint32_t k1, uint32_t j)
{
  uint32_t a, b;
  threefry2x32(k0, k1, 0u, j, a, b);
  return a ^ b;
}

DEVI float jax_bits_to_normal(uint32_t bits)
{
  const float LO = -0.99999994f;
  float f = __uint_as_float((bits >> 9) | 0x3f800000u) - 1.0f;
  float u = fmaxf(LO, f * 2.0f + LO);
  float w = -__logf((1.0f - u) * (1.0f + u));
  float p;
  if (w < 5.0f) {
    w = w - 2.5f;
    p =              2.81022636e-08f;
    p = fmaf(p, w,   3.43273939e-07f);
    p = fmaf(p, w,  -3.5233877e-06f);
    p = fmaf(p, w,  -4.39150654e-06f);
    p = fmaf(p, w,   0.00021858087f);
    p = fmaf(p, w,  -0.00125372503f);
    p = fmaf(p, w,  -0.00417768164f);
    p = fmaf(p, w,   0.246640727f);
    p = fmaf(p, w,   1.50140941f);
  } else {
    w = sqrtf(w) - 3.0f;
    p =             -0.000200214257f;
    p = fmaf(p, w,   0.000100950558f);
    p = fmaf(p, w,   0.00134934322f);
    p = fmaf(p, w,  -0.00367342844f);
    p = fmaf(p, w,   0.00573950773f);
    p = fmaf(p, w,  -0.0076224613f);
    p = fmaf(p, w,   0.00943887047f);
    p = fmaf(p, w,   1.00167406f);
    p = fmaf(p, w,   2.83297682f);
  }
  return 1.41421356237f * (p * u);
}

DEVI short bf16_hi_trunc(float x) { return (short)(__float_as_uint(x) >> 16); }
DEVI float bf16_to_f32(short h)
{
  return __uint_as_float(((uint32_t)(unsigned short)h) << 16);
}
DEVI void split_bf16(float x, short &h, short &l)
{
  h = bf16_hi_trunc(x);
  float r = x - bf16_to_f32(h);
  l = bf16_hi_trunc(r);
}

// 8-short fragment from 16B-aligned LDS (stride-72 rows): one b128 read.
DEVI short8 ld_frag16(const short* p)
{
  union { int4 v; short8 s; } u;
  u.v = *(const int4*)p;
  return u.s;
}

// ---------------------------------------------------------------------------
__global__ __launch_bounds__(256)
void k_pool(const int* __restrict__ seq, const float* __restrict__ emb,
            float* __restrict__ pooled)
{
  const int lane = threadIdx.x & 63;
  const int r    = blockIdx.x * 4 + (threadIdx.x >> 6);
  const int* row = seq + r * 100;
  float s = 0.f;
  int cnt = 0;
  for (int l = 0; l < 100; ++l) {
    int id = row[l];
    cnt += (id != 0);
    s += emb[id * 64 + lane];
  }
  pooled[r * 64 + lane] = s / sqrtf((float)cnt);
}

// ---------------------------------------------------------------------------
__global__ __launch_bounds__(256)
void k_enc(const float* __restrict__ pooled,
           const float* __restrict__ W1, const float* __restrict__ b1,
           const float* __restrict__ W2, const float* __restrict__ b2,
           const float* __restrict__ Wc, const float* __restrict__ bc,
           float* __restrict__ cproj)
{
  __shared__ float p_s[8][64];
  __shared__ float h_s[8][256];
  __shared__ float mu_s[8][64];
  const int tid = threadIdx.x;
  const int r0  = blockIdx.x * 8;

  for (int i = tid; i < 8 * 64; i += 256)
    p_s[i >> 6][i & 63] = pooled[r0 * 64 + i];
  __syncthreads();

  float hacc[8];
#pragma unroll
  for (int r = 0; r < 8; ++r) hacc[r] = b1[tid];
  for (int k = 0; k < 64; ++k) {
    float w = W1[k * 256 + tid];
#pragma unroll
    for (int r = 0; r < 8; ++r) hacc[r] = fmaf(p_s[r][k], w, hacc[r]);
  }
#pragma unroll
  for (int r = 0; r < 8; ++r) h_s[r][tid] = fmaxf(hacc[r], 0.f);
  __syncthreads();

#pragma unroll
  for (int pass = 0; pass < 2; ++pass) {
    int r = pass * 4 + (tid >> 6);
    int j = tid & 63;
    float acc = b2[j];
    for (int k = 0; k < 256; ++k)
      acc = fmaf(h_s[r][k], W2[k * 128 + j], acc);
    mu_s[r][j] = acc;
  }
  __syncthreads();

#pragma unroll
  for (int pass = 0; pass < 2; ++pass) {
    int r = pass * 4 + (tid >> 6);
    int j = tid & 63;
    float acc = bc[j];
    for (int k = 0; k < 64; ++k)
      acc = fmaf(mu_s[r][k], Wc[k * 64 + j], acc);
    cproj[(r0 + r) * 64 + j] = acc;
  }
}

// ---------------------------------------------------------------------------
// k_prep: 200 blocks x 64 threads. Block t computes sched[t*8+..] AND
// tpb[t][d] = temb(t)@W_t + b_t + b_in.
__global__ __launch_bounds__(64)
void k_prep(const float* __restrict__ Wt, const float* __restrict__ bt,
            const float* __restrict__ bin, float* __restrict__ tpb,
            float* __restrict__ sched)
{
  __shared__ float temb[64];
  const int t = blockIdx.x;
  const int d = threadIdx.x;
  const float lg = logf(10000.0f);
  {
    int i = d & 31;
    float fr  = expf((-lg * (float)i) / 32.0f);
    float ang = (float)t * fr;
    temb[d] = (d < 32) ? cosf(ang) : sinf(ang);
  }
  if (d == 0) {
    const float start = (float)(5.0 * 1e-4);
    const float stop  = (float)(5.0 * 0.02);
    const float delta = stop - start;
    float prod = 1.f, acp_prev = 1.f, beta = 0.f, alpha = 1.f;
    for (int i = 0; i <= t; ++i) {
      beta  = start + ((float)i * delta) / 199.0f;
      alpha = 1.0f - beta;
      acp_prev = prod;
      prod = prod * alpha;
    }
    float acp = prod;
    float om  = 1.0f - acp;
    sched[t * 8 + 0] = sqrtf(1.0f / acp);
    sched[t * 8 + 1] = sqrtf(1.0f / acp - 1.0f);
    sched[t * 8 + 2] = beta * sqrtf(acp_prev) / om;
    sched[t * 8 + 3] = (1.0f - acp_prev) * sqrtf(alpha) / om;
    float pv = beta * (1.0f - acp_prev) / om;
    sched[t * 8 + 4] = (t > 0) ? sqrtf(pv) : 0.0f;
    uint32_t fk0, fk1;
    threefry2x32(0u, 2u, 0u, (uint32_t)t, fk0, fk1);
    ((uint32_t*)sched)[t * 8 + 5] = fk0;
    ((uint32_t*)sched)[t * 8 + 6] = fk1;
  }
  __syncthreads();
  float acc = bt[d] + bin[d];
  for (int k = 0; k < 64; ++k)
    acc = fmaf(temb[k], Wt[k * 64 + d], acc);
  tpb[t * 64 + d] = acc;
}

// ---------------------------------------------------------------------------
// K_ddpm: 512 blocks x 512 threads (8 waves). Block owns 16 rows.
// Wave w: nt=w&3 (cols 16nt..16nt+15), kc=w>>2 selects OWNED C-rows only
// (rows quad*4+2kc, +1); every wave computes the FULL K=64 dot (6 MFMA),
// so no partial exchange and only 2 barriers per step.
#define WLDW  72   // weight row stride (shorts); 144 B -> 16B-aligned frags
#define XLDW  72   // X/H row stride (shorts)

__global__
__attribute__((amdgpu_flat_work_group_size(512, 512), amdgpu_waves_per_eu(4, 4)))
void k_ddpm(const float* __restrict__ Win, const float* __restrict__ Wout,
            const float* __restrict__ bout,
            const float* __restrict__ cproj, const float* __restrict__ tpb,
            const float* __restrict__ sched, float* __restrict__ out)
{
  __shared__ __align__(16) short WiHs[64 * WLDW], WiLs[64 * WLDW];
  __shared__ __align__(16) short WoHs[64 * WLDW], WoLs[64 * WLDW];
  __shared__ __align__(16) short Xh[16 * XLDW], Xl[16 * XLDW];
  __shared__ __align__(16) short Hh[16 * XLDW], Hl[16 * XLDW];
  // total: 4*9216 + 4*2304 = 46080 B

  const int tid  = threadIdx.x;
  const int lane = tid & 63;
  const int w    = tid >> 6;
  const int nt   = w & 3;
  const int kc   = w >> 2;
  const int nn   = lane & 15;
  const int quad = lane >> 4;
  const int dim  = nt * 16 + nn;
  const int arow = nn;
  const int r0g  = blockIdx.x * 16;
  const int kq0  = quad * 8;          // K-chunk 0 fragment offset
  const int kq1  = 32 + quad * 8;     // K-chunk 1 fragment offset
  const int rA   = quad * 4 + 2 * kc; // owned C-rows rA, rA+1

  // ---- stage split weights, transposed [n][k]
  for (int idx = tid; idx < 4096; idx += 512) {
    int k = idx >> 6, n = idx & 63;
    short h, l;
    split_bf16(Win[idx], h, l);
    WiHs[n * WLDW + k] = h; WiLs[n * WLDW + k] = l;
    split_bf16(Wout[idx], h, l);
    WoHs[n * WLDW + k] = h; WoLs[n * WLDW + k] = l;
  }

  const float bo = bout[dim];
  const uint32_t jA = (uint32_t)((r0g + rA) * 64 + dim);
  const uint32_t jB = jA + 64u;
  const float cpA = cproj[jA];
  const float cpB = cproj[jB];

  // ---- x_init at owned positions
  float xoA = jax_bits_to_normal(jax_random_bits32(0u, 1u, jA));
  float xoB = jax_bits_to_normal(jax_random_bits32(0u, 1u, jB));
  {
    short h, l;
    split_bf16(xoA, h, l); Xh[rA * XLDW + dim] = h; Xl[rA * XLDW + dim] = l;
    split_bf16(xoB, h, l); Xh[(rA+1) * XLDW + dim] = h; Xl[(rA+1) * XLDW + dim] = l;
  }
  __syncthreads();

  float tp = tpb[199 * 64 + dim];

#pragma unroll 1
  for (int t = 199; t >= 0; --t) {
    const float sr   = sched[t * 8 + 0];
    const float srm1 = sched[t * 8 + 1];
    const float c1   = sched[t * 8 + 2];
    const float c2   = sched[t * 8 + 3];
    const float sg   = sched[t * 8 + 4];
    const uint32_t fk0 = ((const uint32_t*)sched)[t * 8 + 5];
    const uint32_t fk1 = ((const uint32_t*)sched)[t * 8 + 6];

    // noise for owned rows (state-independent; hides under LDS/MFMA latency)
    float nA = jax_bits_to_normal(jax_random_bits32(fk0, fk1, jA));
    float nB = jax_bits_to_normal(jax_random_bits32(fk0, fk1, jB));

    // ---- phase A: in-GEMV, FULL K=64, bias preloaded in owned acc slots
    f32x4 acc;
    if (kc == 0) { acc[0] = tp + cpA; acc[1] = tp + cpB; acc[2] = 0.f; acc[3] = 0.f; }
    else         { acc[0] = 0.f; acc[1] = 0.f; acc[2] = tp + cpA; acc[3] = tp + cpB; }
    {
      short8 xh0 = ld_frag16(&Xh[arow * XLDW + kq0]);
      short8 xl0 = ld_frag16(&Xl[arow * XLDW + kq0]);
      short8 wh0 = ld_frag16(&WiHs[dim * WLDW + kq0]);
      short8 wl0 = ld_frag16(&WiLs[dim * WLDW + kq0]);
      short8 xh1 = ld_frag16(&Xh[arow * XLDW + kq1]);
      short8 xl1 = ld_frag16(&Xl[arow * XLDW + kq1]);
      short8 wh1 = ld_frag16(&WiHs[dim * WLDW + kq1]);
      short8 wl1 = ld_frag16(&WiLs[dim * WLDW + kq1]);
      acc = __builtin_amdgcn_mfma_f32_16x16x32_bf16(xl0, wh0, acc, 0, 0, 0);
      acc = __builtin_amdgcn_mfma_f32_16x16x32_bf16(xh0, wl0, acc, 0, 0, 0);
      acc = __builtin_amdgcn_mfma_f32_16x16x32_bf16(xh0, wh0, acc, 0, 0, 0);
      acc = __builtin_amdgcn_mfma_f32_16x16x32_bf16(xl1, wh1, acc, 0, 0, 0);
      acc = __builtin_amdgcn_mfma_f32_16x16x32_bf16(xh1, wl1, acc, 0, 0, 0);
      acc = __builtin_amdgcn_mfma_f32_16x16x32_bf16(xh1, wh1, acc, 0, 0, 0);
    }
    {
      float vA, vB;
      if (kc == 0) { vA = acc[0]; vB = acc[1]; }
      else         { vA = acc[2]; vB = acc[3]; }
      vA = vA * __builtin_amdgcn_rcpf(1.0f + __expf(-vA));
      vB = vB * __builtin_amdgcn_rcpf(1.0f + __expf(-vB));
      short h, l;
      split_bf16(vA, h, l); Hh[rA * XLDW + dim] = h; Hl[rA * XLDW + dim] = l;
      split_bf16(vB, h, l); Hh[(rA+1) * XLDW + dim] = h; Hl[(rA+1) * XLDW + dim] = l;
    }
    int tn = (t > 0) ? (t - 1) : 0;
    float tpn = tpb[tn * 64 + dim];                     // prefetch next tp
    __syncthreads();                                    // B1

    // ---- phase B: out-GEMV, FULL K=64, then update + restage X
    f32x4 eac;
    if (kc == 0) { eac[0] = bo; eac[1] = bo; eac[2] = 0.f; eac[3] = 0.f; }
    else         { eac[0] = 0.f; eac[1] = 0.f; eac[2] = bo; eac[3] = bo; }
    {
      short8 hh0 = ld_frag16(&Hh[arow * XLDW + kq0]);
      short8 hl0 = ld_frag16(&Hl[arow * XLDW + kq0]);
      short8 wh0 = ld_frag16(&WoHs[dim * WLDW + kq0]);
      short8 wl0 = ld_frag16(&WoLs[dim * WLDW + kq0]);
      short8 hh1 = ld_frag16(&Hh[arow * XLDW + kq1]);
      short8 hl1 = ld_frag16(&Hl[arow * XLDW + kq1]);
      short8 wh1 = ld_frag16(&WoHs[dim * WLDW + kq1]);
      short8 wl1 = ld_frag16(&WoLs[dim * WLDW + kq1]);
      eac = __builtin_amdgcn_mfma_f32_16x16x32_bf16(hl0, wh0, eac, 0, 0, 0);
      eac = __builtin_amdgcn_mfma_f32_16x16x32_bf16(hh0, wl0, eac, 0, 0, 0);
      eac = __builtin_amdgcn_mfma_f32_16x16x32_bf16(hh0, wh0, eac, 0, 0, 0);
      eac = __builtin_amdgcn_mfma_f32_16x16x32_bf16(hl1, wh1, eac, 0, 0, 0);
      eac = __builtin_amdgcn_mfma_f32_16x16x32_bf16(hh1, wl1, eac, 0, 0, 0);
      eac = __builtin_amdgcn_mfma_f32_16x16x32_bf16(hh1, wh1, eac, 0, 0, 0);
    }
    {
      float eA, eB;
      if (kc == 0) { eA = eac[0]; eB = eac[1]; }
      else         { eA = eac[2]; eB = eac[3]; }
      float xcA = fminf(1.f, fmaxf(-1.f, sr * xoA - srm1 * eA));
      float xcB = fminf(1.f, fmaxf(-1.f, sr * xoB - srm1 * eB));
      xoA = c1 * xcA + c2 * xoA + sg * nA;
      xoB = c1 * xcB + c2 * xoB + sg * nB;
      short h, l;
      split_bf16(xoA, h, l); Xh[rA * XLDW + dim] = h; Xl[rA * XLDW + dim] = l;
      split_bf16(xoB, h, l); Xh[(rA+1) * XLDW + dim] = h; Xl[(rA+1) * XLDW + dim] = l;
      tp = tpn;
    }
    __syncthreads();                                    // B2
  }

  out[jA] = xoA;
  out[jB] = xoB;
}

// ---------------------------------------------------------------------------
extern "C" void kernel_launch(void* const* d_in, const int* in_sizes, int n_in,
                              void* d_out, int out_size, void* d_ws, size_t ws_size,
                              hipStream_t stream)
{
  const int*   seq  = (const int*)  d_in[0];
  const float* emb  = (const float*)d_in[1];
  const float* W1   = (const float*)d_in[2];
  const float* b1   = (const float*)d_in[3];
  const float* W2   = (const float*)d_in[4];
  const float* b2   = (const float*)d_in[5];
  const float* Win  = (const float*)d_in[6];
  const float* bin  = (const float*)d_in[7];
  const float* Wt   = (const float*)d_in[8];
  const float* bt   = (const float*)d_in[9];
  const float* Wc   = (const float*)d_in[10];
  const float* bc   = (const float*)d_in[11];
  const float* Wout = (const float*)d_in[12];
  const float* bout = (const float*)d_in[13];

  float* out   = (float*)d_out;
  float* ws    = (float*)d_ws;
  float* cproj = ws;                       // 524288 floats
  float* tpb   = ws + 524288;              // 12800 floats
  float* sched = ws + 524288 + 12800;      // 1600 floats (t*8 layout)
  float* pooled = out;                     // reuse d_out as scratch

  k_pool <<<2048, 256, 0, stream>>>(seq, emb, pooled);
  k_enc  <<<1024, 256, 0, stream>>>(pooled, W1, b1, W2, b2, Wc, bc, cproj);
  k_prep <<<200, 64, 0, stream>>>(Wt, bt, bin, tpb, sched);
  k_ddpm <<<512, 512, 0, stream>>>(Win, Wout, bout, cproj, tpb, sched, out);
}

// Round 4
// 561.424 us; speedup vs baseline: 1.3978x; 1.0535x over previous
//
#include <hip/hip_runtime.h>
#include <cstdint>

// ---------------------------------------------------------------------------
// DDPM + VAE query encoder, MI355X round 16.
// r15 post-mortem: full-K duplication halved barriers but DOUBLED LDS reads
// (16 b128/wave/step = 256 KB/CU/step ~ 3000 cy of the 6000-cy step; bank
// "conflicts" 53M are mostly the b128 wave64 8-cy floor). LDS bandwidth is
// now a dominant pipe. Fix: weights are loop-invariant but were re-read from
// LDS 200x. Hoist all weight fragments into registers (8 x short8 = 32 VGPR,
// budget 128, have 52):
//  - per-step LDS reads halve to 8/wave (X/H only)
//  - weight LDS arrays deleted: LDS 46 KB -> 9.2 KB
//  - staging loop deleted; weight frags loaded global->reg at init
// Bit-identical arithmetic to r15 (same split values, same MFMA order).
// ---------------------------------------------------------------------------

#define DEVI __device__ __forceinline__

typedef __attribute__((ext_vector_type(8))) short short8;
typedef __attribute__((ext_vector_type(4))) float f32x4;

DEVI void threefry2x32(uint32_t k0, uint32_t k1, uint32_t x0, uint32_t x1,
                       uint32_t &o0, uint32_t &o1)
{
  const uint32_t ks2 = k0 ^ k1 ^ 0x1BD11BDAu;
  x0 += k0; x1 += k1;
#define TFR(r) { x0 += x1; x1 = __builtin_rotateleft32(x1, r); x1 ^= x0; }
  TFR(13u) TFR(15u) TFR(26u) TFR(6u)   x0 += k1;  x1 += ks2 + 1u;
  TFR(17u) TFR(29u) TFR(16u) TFR(24u)  x0 += ks2; x1 += k0 + 2u;
  TFR(13u) TFR(15u) TFR(26u) TFR(6u)   x0 += k0;  x1 += k1 + 3u;
  TFR(17u) TFR(29u) TFR(16u) TFR(24u)  x0 += k1;  x1 += ks2 + 4u;
  TFR(13u) TFR(15u) TFR(26u) TFR(6u)   x0 += ks2; x1 += k0 + 5u;
#undef TFR
  o0 = x0; o1 = x1;
}

DEVI uint32_t jax_random_bits32(uint32_t k0, uint32_t k1, uint32_t j)
{
  uint32_t a, b;
  threefry2x32(k0, k1, 0u, j, a, b);
  return a ^ b;
}

DEVI float jax_bits_to_normal(uint32_t bits)
{
  const float LO = -0.99999994f;
  float f = __uint_as_float((bits >> 9) | 0x3f800000u) - 1.0f;
  float u = fmaxf(LO, f * 2.0f + LO);
  float w = -__logf((1.0f - u) * (1.0f + u));
  float p;
  if (w < 5.0f) {
    w = w - 2.5f;
    p =              2.81022636e-08f;
    p = fmaf(p, w,   3.43273939e-07f);
    p = fmaf(p, w,  -3.5233877e-06f);
    p = fmaf(p, w,  -4.39150654e-06f);
    p = fmaf(p, w,   0.00021858087f);
    p = fmaf(p, w,  -0.00125372503f);
    p = fmaf(p, w,  -0.00417768164f);
    p = fmaf(p, w,   0.246640727f);
    p = fmaf(p, w,   1.50140941f);
  } else {
    w = sqrtf(w) - 3.0f;
    p =             -0.000200214257f;
    p = fmaf(p, w,   0.000100950558f);
    p = fmaf(p, w,   0.00134934322f);
    p = fmaf(p, w,  -0.00367342844f);
    p = fmaf(p, w,   0.00573950773f);
    p = fmaf(p, w,  -0.0076224613f);
    p = fmaf(p, w,   0.00943887047f);
    p = fmaf(p, w,   1.00167406f);
    p = fmaf(p, w,   2.83297682f);
  }
  return 1.41421356237f * (p * u);
}

DEVI short bf16_hi_trunc(float x) { return (short)(__float_as_uint(x) >> 16); }
DEVI float bf16_to_f32(short h)
{
  return __uint_as_float(((uint32_t)(unsigned short)h) << 16);
}
DEVI void split_bf16(float x, short &h, short &l)
{
  h = bf16_hi_trunc(x);
  float r = x - bf16_to_f32(h);
  l = bf16_hi_trunc(r);
}

// 8-short fragment from 16B-aligned LDS (stride-72 rows): one b128 read.
DEVI short8 ld_frag16(const short* p)
{
  union { int4 v; short8 s; } u;
  u.v = *(const int4*)p;
  return u.s;
}

// ---------------------------------------------------------------------------
__global__ __launch_bounds__(256)
void k_pool(const int* __restrict__ seq, const float* __restrict__ emb,
            float* __restrict__ pooled)
{
  const int lane = threadIdx.x & 63;
  const int r    = blockIdx.x * 4 + (threadIdx.x >> 6);
  const int* row = seq + r * 100;
  float s = 0.f;
  int cnt = 0;
  for (int l = 0; l < 100; ++l) {
    int id = row[l];
    cnt += (id != 0);
    s += emb[id * 64 + lane];
  }
  pooled[r * 64 + lane] = s / sqrtf((float)cnt);
}

// ---------------------------------------------------------------------------
__global__ __launch_bounds__(256)
void k_enc(const float* __restrict__ pooled,
           const float* __restrict__ W1, const float* __restrict__ b1,
           const float* __restrict__ W2, const float* __restrict__ b2,
           const float* __restrict__ Wc, const float* __restrict__ bc,
           float* __restrict__ cproj)
{
  __shared__ float p_s[8][64];
  __shared__ float h_s[8][256];
  __shared__ float mu_s[8][64];
  const int tid = threadIdx.x;
  const int r0  = blockIdx.x * 8;

  for (int i = tid; i < 8 * 64; i += 256)
    p_s[i >> 6][i & 63] = pooled[r0 * 64 + i];
  __syncthreads();

  float hacc[8];
#pragma unroll
  for (int r = 0; r < 8; ++r) hacc[r] = b1[tid];
  for (int k = 0; k < 64; ++k) {
    float w = W1[k * 256 + tid];
#pragma unroll
    for (int r = 0; r < 8; ++r) hacc[r] = fmaf(p_s[r][k], w, hacc[r]);
  }
#pragma unroll
  for (int r = 0; r < 8; ++r) h_s[r][tid] = fmaxf(hacc[r], 0.f);
  __syncthreads();

#pragma unroll
  for (int pass = 0; pass < 2; ++pass) {
    int r = pass * 4 + (tid >> 6);
    int j = tid & 63;
    float acc = b2[j];
    for (int k = 0; k < 256; ++k)
      acc = fmaf(h_s[r][k], W2[k * 128 + j], acc);
    mu_s[r][j] = acc;
  }
  __syncthreads();

#pragma unroll
  for (int pass = 0; pass < 2; ++pass) {
    int r = pass * 4 + (tid >> 6);
    int j = tid & 63;
    float acc = bc[j];
    for (int k = 0; k < 64; ++k)
      acc = fmaf(mu_s[r][k], Wc[k * 64 + j], acc);
    cproj[(r0 + r) * 64 + j] = acc;
  }
}

// ---------------------------------------------------------------------------
// k_prep: 200 blocks x 64 threads. Block t computes sched[t*8+..] AND
// tpb[t][d] = temb(t)@W_t + b_t + b_in.
__global__ __launch_bounds__(64)
void k_prep(const float* __restrict__ Wt, const float* __restrict__ bt,
            const float* __restrict__ bin, float* __restrict__ tpb,
            float* __restrict__ sched)
{
  __shared__ float temb[64];
  const int t = blockIdx.x;
  const int d = threadIdx.x;
  const float lg = logf(10000.0f);
  {
    int i = d & 31;
    float fr  = expf((-lg * (float)i) / 32.0f);
    float ang = (float)t * fr;
    temb[d] = (d < 32) ? cosf(ang) : sinf(ang);
  }
  if (d == 0) {
    const float start = (float)(5.0 * 1e-4);
    const float stop  = (float)(5.0 * 0.02);
    const float delta = stop - start;
    float prod = 1.f, acp_prev = 1.f, beta = 0.f, alpha = 1.f;
    for (int i = 0; i <= t; ++i) {
      beta  = start + ((float)i * delta) / 199.0f;
      alpha = 1.0f - beta;
      acp_prev = prod;
      prod = prod * alpha;
    }
    float acp = prod;
    float om  = 1.0f - acp;
    sched[t * 8 + 0] = sqrtf(1.0f / acp);
    sched[t * 8 + 1] = sqrtf(1.0f / acp - 1.0f);
    sched[t * 8 + 2] = beta * sqrtf(acp_prev) / om;
    sched[t * 8 + 3] = (1.0f - acp_prev) * sqrtf(alpha) / om;
    float pv = beta * (1.0f - acp_prev) / om;
    sched[t * 8 + 4] = (t > 0) ? sqrtf(pv) : 0.0f;
    uint32_t fk0, fk1;
    threefry2x32(0u, 2u, 0u, (uint32_t)t, fk0, fk1);
    ((uint32_t*)sched)[t * 8 + 5] = fk0;
    ((uint32_t*)sched)[t * 8 + 6] = fk1;
  }
  __syncthreads();
  float acc = bt[d] + bin[d];
  for (int k = 0; k < 64; ++k)
    acc = fmaf(temb[k], Wt[k * 64 + d], acc);
  tpb[t * 64 + d] = acc;
}

// ---------------------------------------------------------------------------
// K_ddpm: 512 blocks x 512 threads (8 waves). Block owns 16 rows.
// Wave w: nt=w&3 (cols 16nt..16nt+15), kc=w>>2 selects OWNED C-rows only
// (rows quad*4+2kc, +1); every wave computes the FULL K=64 dot (6 MFMA).
// Weight B-fragments live in REGISTERS (32 VGPR); LDS holds only X/H.
#define XLDW  72   // X/H row stride (shorts); 144 B -> 16B-aligned frags

__global__
__attribute__((amdgpu_flat_work_group_size(512, 512), amdgpu_waves_per_eu(4, 4)))
void k_ddpm(const float* __restrict__ Win, const float* __restrict__ Wout,
            const float* __restrict__ bout,
            const float* __restrict__ cproj, const float* __restrict__ tpb,
            const float* __restrict__ sched, float* __restrict__ out)
{
  __shared__ __align__(16) short Xh[16 * XLDW], Xl[16 * XLDW];
  __shared__ __align__(16) short Hh[16 * XLDW], Hl[16 * XLDW];
  // total: 4*2304 = 9216 B

  const int tid  = threadIdx.x;
  const int lane = tid & 63;
  const int w    = tid >> 6;
  const int nt   = w & 3;
  const int kc   = w >> 2;
  const int nn   = lane & 15;
  const int quad = lane >> 4;
  const int dim  = nt * 16 + nn;
  const int arow = nn;
  const int r0g  = blockIdx.x * 16;
  const int kq0  = quad * 8;          // K-chunk 0 fragment offset
  const int kq1  = 32 + quad * 8;     // K-chunk 1 fragment offset
  const int rA   = quad * 4 + 2 * kc; // owned C-rows rA, rA+1

  // ---- weight B-fragments -> registers (bit-identical to LDS staging path)
  short8 wiH0, wiL0, wiH1, wiL1, woH0, woL0, woH1, woL1;
#pragma unroll
  for (int j = 0; j < 8; ++j) {
    short h, l;
    split_bf16(Win[(kq0 + j) * 64 + dim], h, l);  wiH0[j] = h; wiL0[j] = l;
    split_bf16(Win[(kq1 + j) * 64 + dim], h, l);  wiH1[j] = h; wiL1[j] = l;
    split_bf16(Wout[(kq0 + j) * 64 + dim], h, l); woH0[j] = h; woL0[j] = l;
    split_bf16(Wout[(kq1 + j) * 64 + dim], h, l); woH1[j] = h; woL1[j] = l;
  }

  const float bo = bout[dim];
  const uint32_t jA = (uint32_t)((r0g + rA) * 64 + dim);
  const uint32_t jB = jA + 64u;
  const float cpA = cproj[jA];
  const float cpB = cproj[jB];

  // ---- x_init at owned positions
  float xoA = jax_bits_to_normal(jax_random_bits32(0u, 1u, jA));
  float xoB = jax_bits_to_normal(jax_random_bits32(0u, 1u, jB));
  {
    short h, l;
    split_bf16(xoA, h, l); Xh[rA * XLDW + dim] = h; Xl[rA * XLDW + dim] = l;
    split_bf16(xoB, h, l); Xh[(rA+1) * XLDW + dim] = h; Xl[(rA+1) * XLDW + dim] = l;
  }
  __syncthreads();

  float tp = tpb[199 * 64 + dim];

#pragma unroll 1
  for (int t = 199; t >= 0; --t) {
    const float sr   = sched[t * 8 + 0];
    const float srm1 = sched[t * 8 + 1];
    const float c1   = sched[t * 8 + 2];
    const float c2   = sched[t * 8 + 3];
    const float sg   = sched[t * 8 + 4];
    const uint32_t fk0 = ((const uint32_t*)sched)[t * 8 + 5];
    const uint32_t fk1 = ((const uint32_t*)sched)[t * 8 + 6];

    // noise for owned rows (state-independent; hides under LDS/MFMA latency)
    float nA = jax_bits_to_normal(jax_random_bits32(fk0, fk1, jA));
    float nB = jax_bits_to_normal(jax_random_bits32(fk0, fk1, jB));

    // ---- phase A: in-GEMV, FULL K=64, bias preloaded in owned acc slots
    f32x4 acc;
    if (kc == 0) { acc[0] = tp + cpA; acc[1] = tp + cpB; acc[2] = 0.f; acc[3] = 0.f; }
    else         { acc[0] = 0.f; acc[1] = 0.f; acc[2] = tp + cpA; acc[3] = tp + cpB; }
    {
      short8 xh0 = ld_frag16(&Xh[arow * XLDW + kq0]);
      short8 xl0 = ld_frag16(&Xl[arow * XLDW + kq0]);
      short8 xh1 = ld_frag16(&Xh[arow * XLDW + kq1]);
      short8 xl1 = ld_frag16(&Xl[arow * XLDW + kq1]);
      acc = __builtin_amdgcn_mfma_f32_16x16x32_bf16(xl0, wiH0, acc, 0, 0, 0);
      acc = __builtin_amdgcn_mfma_f32_16x16x32_bf16(xh0, wiL0, acc, 0, 0, 0);
      acc = __builtin_amdgcn_mfma_f32_16x16x32_bf16(xh0, wiH0, acc, 0, 0, 0);
      acc = __builtin_amdgcn_mfma_f32_16x16x32_bf16(xl1, wiH1, acc, 0, 0, 0);
      acc = __builtin_amdgcn_mfma_f32_16x16x32_bf16(xh1, wiL1, acc, 0, 0, 0);
      acc = __builtin_amdgcn_mfma_f32_16x16x32_bf16(xh1, wiH1, acc, 0, 0, 0);
    }
    {
      float vA, vB;
      if (kc == 0) { vA = acc[0]; vB = acc[1]; }
      else         { vA = acc[2]; vB = acc[3]; }
      vA = vA * __builtin_amdgcn_rcpf(1.0f + __expf(-vA));
      vB = vB * __builtin_amdgcn_rcpf(1.0f + __expf(-vB));
      short h, l;
      split_bf16(vA, h, l); Hh[rA * XLDW + dim] = h; Hl[rA * XLDW + dim] = l;
      split_bf16(vB, h, l); Hh[(rA+1) * XLDW + dim] = h; Hl[(rA+1) * XLDW + dim] = l;
    }
    int tn = (t > 0) ? (t - 1) : 0;
    float tpn = tpb[tn * 64 + dim];                     // prefetch next tp
    __syncthreads();                                    // B1

    // ---- phase B: out-GEMV, FULL K=64, then update + restage X
    f32x4 eac;
    if (kc == 0) { eac[0] = bo; eac[1] = bo; eac[2] = 0.f; eac[3] = 0.f; }
    else         { eac[0] = 0.f; eac[1] = 0.f; eac[2] = bo; eac[3] = bo; }
    {
      short8 hh0 = ld_frag16(&Hh[arow * XLDW + kq0]);
      short8 hl0 = ld_frag16(&Hl[arow * XLDW + kq0]);
      short8 hh1 = ld_frag16(&Hh[arow * XLDW + kq1]);
      short8 hl1 = ld_frag16(&Hl[arow * XLDW + kq1]);
      eac = __builtin_amdgcn_mfma_f32_16x16x32_bf16(hl0, woH0, eac, 0, 0, 0);
      eac = __builtin_amdgcn_mfma_f32_16x16x32_bf16(hh0, woL0, eac, 0, 0, 0);
      eac = __builtin_amdgcn_mfma_f32_16x16x32_bf16(hh0, woH0, eac, 0, 0, 0);
      eac = __builtin_amdgcn_mfma_f32_16x16x32_bf16(hl1, woH1, eac, 0, 0, 0);
      eac = __builtin_amdgcn_mfma_f32_16x16x32_bf16(hh1, woL1, eac, 0, 0, 0);
      eac = __builtin_amdgcn_mfma_f32_16x16x32_bf16(hh1, woH1, eac, 0, 0, 0);
    }
    {
      float eA, eB;
      if (kc == 0) { eA = eac[0]; eB = eac[1]; }
      else         { eA = eac[2]; eB = eac[3]; }
      float xcA = fminf(1.f, fmaxf(-1.f, sr * xoA - srm1 * eA));
      float xcB = fminf(1.f, fmaxf(-1.f, sr * xoB - srm1 * eB));
      xoA = c1 * xcA + c2 * xoA + sg * nA;
      xoB = c1 * xcB + c2 * xoB + sg * nB;
      short h, l;
      split_bf16(xoA, h, l); Xh[rA * XLDW + dim] = h; Xl[rA * XLDW + dim] = l;
      split_bf16(xoB, h, l); Xh[(rA+1) * XLDW + dim] = h; Xl[(rA+1) * XLDW + dim] = l;
      tp = tpn;
    }
    __syncthreads();                                    // B2
  }

  out[jA] = xoA;
  out[jB] = xoB;
}

// ---------------------------------------------------------------------------
extern "C" void kernel_launch(void* const* d_in, const int* in_sizes, int n_in,
                              void* d_out, int out_size, void* d_ws, size_t ws_size,
                              hipStream_t stream)
{
  const int*   seq  = (const int*)  d_in[0];
  const float* emb  = (const float*)d_in[1];
  const float* W1   = (const float*)d_in[2];
  const float* b1   = (const float*)d_in[3];
  const float* W2   = (const float*)d_in[4];
  const float* b2   = (const float*)d_in[5];
  const float* Win  = (const float*)d_in[6];
  const float* bin  = (const float*)d_in[7];
  const float* Wt   = (const float*)d_in[8];
  const float* bt   = (const float*)d_in[9];
  const float* Wc   = (const float*)d_in[10];
  const float* bc   = (const float*)d_in[11];
  const float* Wout = (const float*)d_in[12];
  const float* bout = (const float*)d_in[13];

  float* out   = (float*)d_out;
  float* ws    = (float*)d_ws;
  float* cproj = ws;                       // 524288 floats
  float* tpb   = ws + 524288;              // 12800 floats
  float* sched = ws + 524288 + 12800;      // 1600 floats (t*8 layout)
  float* pooled = out;                     // reuse d_out as scratch

  k_pool <<<2048, 256, 0, stream>>>(seq, emb, pooled);
  k_enc  <<<1024, 256, 0, stream>>>(pooled, W1, b1, W2, b2, Wc, bc, cproj);
  k_prep <<<200, 64, 0, stream>>>(Wt, bt, bin, tpb, sched);
  k_ddpm <<<512, 512, 0, stream>>>(Win, Wout, bout, cproj, tpb, sched, out);
}